// Round 5
// baseline (591.638 us; speedup 1.0000x reference)
//
#include <hip/hip_runtime.h>

#define B_ 4
#define N_ 2048
#define D_ 768
#define H_ 12
#define DH_ 64
#define ROWS_ (B_*N_)      // 8192
#define E3_ (3*D_)         // 2304

typedef _Float16 f16;
typedef __attribute__((ext_vector_type(8))) _Float16 half8;
typedef __attribute__((ext_vector_type(4))) float floatx4;

__device__ __forceinline__ void gload_lds16(const void* g, void* lds){
  __builtin_amdgcn_global_load_lds(
      (const __attribute__((address_space(1))) unsigned int*)g,
      (__attribute__((address_space(3))) unsigned int*)lds, 16, 0, 0);
}

// ---------------- 0) fp32 -> fp16 weight convert ----------------
__global__ __launch_bounds__(256) void cvt_kernel(const float* __restrict__ src,
    f16* __restrict__ dst, int n8){
  int i = blockIdx.x*256 + threadIdx.x;
  if (i < n8){
    float4 a = ((const float4*)src)[2*i];
    float4 b = ((const float4*)src)[2*i+1];
    half8 h;
    h[0]=(f16)a.x; h[1]=(f16)a.y; h[2]=(f16)a.z; h[3]=(f16)a.w;
    h[4]=(f16)b.x; h[5]=(f16)b.y; h[6]=(f16)b.z; h[7]=(f16)b.w;
    *(half8*)(dst + (size_t)i*8) = h;
  }
}

// ---------------- 1) LayerNorm: x (fp32) -> xn (fp16) ----------------
__global__ __launch_bounds__(256) void ln_kernel(const float* __restrict__ x,
    const float* __restrict__ g, const float* __restrict__ be, f16* __restrict__ xn){
  int row = blockIdx.x;
  const float* xr = x + (size_t)row * D_;
  int t = threadIdx.x;
  float v0 = xr[t], v1 = xr[t+256], v2 = xr[t+512];
  float s = v0+v1+v2, ss = v0*v0+v1*v1+v2*v2;
  #pragma unroll
  for(int off=32; off; off>>=1){
    s  += __shfl_down(s,  off, 64);
    ss += __shfl_down(ss, off, 64);
  }
  __shared__ float red[2][4];
  int lane = t & 63, wv = t >> 6;
  if(lane==0){ red[0][wv]=s; red[1][wv]=ss; }
  __syncthreads();
  s  = red[0][0]+red[0][1]+red[0][2]+red[0][3];
  ss = red[1][0]+red[1][1]+red[1][2]+red[1][3];
  float mean = s * (1.0f/D_);
  float var  = ss * (1.0f/D_) - mean*mean;
  float rstd = rsqrtf(var + 1e-5f);
  f16* xo = xn + (size_t)row * D_;
  xo[t]     = (f16)((v0-mean)*rstd*g[t]     + be[t]);
  xo[t+256] = (f16)((v1-mean)*rstd*g[t+256] + be[t+256]);
  xo[t+512] = (f16)((v2-mean)*rstd*g[t+512] + be[t+512]);
}

// ---------------- 2) QKV GEMM (MFMA) ----------------
__global__ __launch_bounds__(256) void qkv_gemm(const f16* __restrict__ A,
    const f16* __restrict__ W, f16* __restrict__ Q, f16* __restrict__ Kt, f16* __restrict__ VT){
  __shared__ f16 sA[128*32];
  __shared__ f16 sB[128*32];
  int tid = threadIdx.x;
  int w = tid >> 6, lane = tid & 63, quad = lane >> 4, l15 = lane & 15;
  int row0 = blockIdx.y * 128;
  int e0   = blockIdx.x * 128;
  int wr = (w >> 1) * 64, wc = (w & 1) * 64;
  int r0c = tid >> 2,        ci0 = (tid & 3) * 8;
  int r1c = (256+tid) >> 2,  ci1 = (tid & 3) * 8;
  floatx4 acc[4][4];
  #pragma unroll
  for(int i=0;i<4;++i)
    #pragma unroll
    for(int j=0;j<4;++j) acc[i][j] = (floatx4){0.f,0.f,0.f,0.f};

  for(int k0=0; k0<D_; k0+=32){
    __syncthreads();
    gload_lds16(A + (size_t)(row0+r0c)*D_ + k0 + ci0, sA + (size_t)(w*64)*8);
    gload_lds16(A + (size_t)(row0+r1c)*D_ + k0 + ci1, sA + (size_t)(256 + w*64)*8);
    gload_lds16(W + (size_t)(e0 +r0c)*D_ + k0 + ci0, sB + (size_t)(w*64)*8);
    gload_lds16(W + (size_t)(e0 +r1c)*D_ + k0 + ci1, sB + (size_t)(256 + w*64)*8);
    __syncthreads();
    half8 af[4], bf[4];
    #pragma unroll
    for(int mi=0;mi<4;++mi) af[mi] = *(const half8*)&sA[(wr + mi*16 + l15)*32 + quad*8];
    #pragma unroll
    for(int ni=0;ni<4;++ni) bf[ni] = *(const half8*)&sB[(wc + ni*16 + l15)*32 + quad*8];
    #pragma unroll
    for(int mi=0;mi<4;++mi)
      #pragma unroll
      for(int ni=0;ni<4;++ni)
        acc[mi][ni] = __builtin_amdgcn_mfma_f32_16x16x32_f16(af[mi], bf[ni], acc[mi][ni], 0, 0, 0);
  }
  int part = e0 / D_;
  int erel = e0 % D_;
  #pragma unroll
  for(int ni=0;ni<4;++ni){
    int col = erel + wc + ni*16 + l15;
    int h = col >> 6, d = col & 63;
    #pragma unroll
    for(int mi=0;mi<4;++mi){
      int rbase = row0 + wr + mi*16 + quad*4;
      #pragma unroll
      for(int reg=0;reg<4;++reg){
        int r = rbase + reg;
        int b = r >> 11, n = r & 2047;
        f16 val = (f16)acc[mi][ni][reg];
        if (part == 0)
          Q [(((size_t)b*H_ + h)*N_ + n)*DH_ + d] = val;
        else if (part == 1)
          Kt[(((size_t)b*H_ + h)*N_ + n)*DH_ + d] = val;
        else
          VT[(((size_t)b*H_ + h)*DH_ + d)*N_ + n] = val;   // transposed
      }
    }
  }
}

// ---------------- 3) RoPE ----------------
__global__ __launch_bounds__(256) void rope_kernel(f16* __restrict__ Q, f16* __restrict__ K,
    const float* __restrict__ coords){
  int t = blockIdx.x*256 + threadIdx.x;
  const int total = B_*H_*N_;
  f16* basep; int idx;
  if (t < total){ basep = Q; idx = t; } else { basep = K; idx = t - total; }
  int n  = idx % N_;
  int bh = idx / N_;
  int b  = bh / H_;
  float c0 = coords[((size_t)b*N_+n)*2 + 0];
  float c1 = coords[((size_t)b*N_+n)*2 + 1];
  f16* rowp = basep + (size_t)idx * DH_;
  #pragma unroll
  for(int ax=0; ax<2; ++ax){
    float coord = ax ? c1 : c0;
    int base = ax*32;
    float tv[32];
    #pragma unroll
    for(int i=0;i<32;++i) tv[i] = (float)rowp[base+i];
    #pragma unroll
    for(int m=0;m<16;++m){
      float fr = exp2f((float)m * (-13.0f/16.0f));
      float ph = coord * fr;
      float sn, cs;
      sincosf(ph, &sn, &cs);
      rowp[base+m]    = (f16)(tv[2*m]*cs - tv[2*m+1]*sn);
      rowp[base+16+m] = (f16)(tv[2*m]*sn + tv[2*m+1]*cs);
    }
  }
}

// ---------------- 4) Flash attention, MFMA fp16, BARRIER-FREE main loop ----------------
// Each wave owns 16 q rows and computes the FULL O^T (64 d) for them.
// P transpose goes through a wave-PRIVATE LDS tile -> no __syncthreads anywhere.
#define PITCH_ 68
__global__ __launch_bounds__(256) void attn_kernel(const f16* __restrict__ Q,
    const f16* __restrict__ K, const f16* __restrict__ VT, f16* __restrict__ AO){
  __shared__ f16 sP[4][16*PITCH_];     // per-wave private
  int bh = blockIdx.y;
  int q0 = blockIdx.x * 64;
  int tid = threadIdx.x;
  int w = tid >> 6, lane = tid & 63, quad = lane >> 4, l15 = lane & 15;
  const f16* Qb = Q  + (size_t)bh*N_*DH_;
  const f16* Ks = K  + (size_t)bh*N_*DH_;
  const f16* Vb = VT + (size_t)bh*DH_*N_;   // [d][n]
  f16* myP = &sP[w][0];

  const f16* qrow = Qb + (size_t)(q0 + 16*w + l15)*DH_ + quad*8;
  half8 qf0 = *(const half8*)(qrow);
  half8 qf1 = *(const half8*)(qrow + 32);

  // preload K fragments for kv0 = 0
  half8 kf0[4], kf1[4];
  #pragma unroll
  for(int nt=0;nt<4;++nt){
    const f16* krow = Ks + (size_t)(16*nt + l15)*DH_ + quad*8;
    kf0[nt] = *(const half8*)(krow);
    kf1[nt] = *(const half8*)(krow + 32);
  }

  float m_prev[4], l_run[4];
  #pragma unroll
  for(int r=0;r<4;++r){ m_prev[r] = -1e30f; l_run[r] = 0.0f; }
  floatx4 acc[4];                      // O^T: acc[dt][reg] = O^T[16dt+quad*4+reg][q=l15]
  #pragma unroll
  for(int dt=0;dt<4;++dt) acc[dt] = (floatx4){0.f,0.f,0.f,0.f};

  int shsrc = ((l15 >> 2) << 4) + l15;   // a lane whose quad == l15>>2

  for(int kv0=0; kv0<N_; kv0+=64){
    // V^T fragments for this tile: 4 d-strips x 2 k-halves (consumed after softmax)
    half8 vf0[4], vf1[4];
    #pragma unroll
    for(int dt=0;dt<4;++dt){
      const f16* vr = Vb + (size_t)(16*dt + l15)*N_ + kv0 + quad*8;
      vf0[dt] = *(const half8*)(vr);
      vf1[dt] = *(const half8*)(vr + 32);
    }
    // ---- S = Q K^T (own 16 q rows x 64 kv) ----
    floatx4 s[4];
    #pragma unroll
    for(int nt=0; nt<4; ++nt){
      floatx4 z = {0.f,0.f,0.f,0.f};
      z = __builtin_amdgcn_mfma_f32_16x16x32_f16(qf0, kf0[nt], z, 0, 0, 0);
      z = __builtin_amdgcn_mfma_f32_16x16x32_f16(qf1, kf1[nt], z, 0, 0, 0);
      s[nt] = z;
    }
    // ---- online softmax (rows quad*4+r, cols l15+16nt) ----
    #pragma unroll
    for(int nt=0;nt<4;++nt)
      #pragma unroll
      for(int r=0;r<4;++r) s[nt][r] *= 0.125f;
    float mx[4], alpha[4], rs[4];
    #pragma unroll
    for(int r=0;r<4;++r)
      mx[r] = fmaxf(fmaxf(s[0][r], s[1][r]), fmaxf(s[2][r], s[3][r]));
    #pragma unroll
    for(int off=1; off<16; off<<=1){
      #pragma unroll
      for(int r=0;r<4;++r) mx[r] = fmaxf(mx[r], __shfl_xor(mx[r], off, 64));
    }
    #pragma unroll
    for(int r=0;r<4;++r){
      float mnew = fmaxf(m_prev[r], mx[r]);
      alpha[r] = __expf(m_prev[r] - mnew);
      m_prev[r] = mnew;
      rs[r] = 0.0f;
    }
    #pragma unroll
    for(int nt=0;nt<4;++nt){
      #pragma unroll
      for(int r=0;r<4;++r){
        float p = __expf(s[nt][r] - m_prev[r]);
        s[nt][r] = p;
        rs[r] += p;
      }
    }
    #pragma unroll
    for(int off=1; off<16; off<<=1){
      #pragma unroll
      for(int r=0;r<4;++r) rs[r] += __shfl_xor(rs[r], off, 64);
    }
    #pragma unroll
    for(int r=0;r<4;++r) l_run[r] = l_run[r]*alpha[r] + rs[r];
    // ---- write P to wave-private LDS (C-layout -> [q][kv]) ----
    #pragma unroll
    for(int nt=0;nt<4;++nt)
      #pragma unroll
      for(int r=0;r<4;++r)
        myP[(quad*4 + r)*PITCH_ + l15 + 16*nt] = (f16)s[nt][r];
    // ---- prefetch K fragments for NEXT tile (hidden behind PV) ----
    {
      int kvn = kv0 + 64; if (kvn >= N_) kvn = 0;
      #pragma unroll
      for(int nt=0;nt<4;++nt){
        const f16* krow = Ks + (size_t)(kvn + 16*nt + l15)*DH_ + quad*8;
        kf0[nt] = *(const half8*)(krow);
        kf1[nt] = *(const half8*)(krow + 32);
      }
    }
    // ---- alpha for this lane's O^T column q=l15 (shfl broadcast + select) ----
    float av0 = __shfl(alpha[0], shsrc, 64);
    float av1 = __shfl(alpha[1], shsrc, 64);
    float av2 = __shfl(alpha[2], shsrc, 64);
    float av3 = __shfl(alpha[3], shsrc, 64);
    float aq = (l15 & 2) ? ((l15 & 1) ? av3 : av2) : ((l15 & 1) ? av1 : av0);
    #pragma unroll
    for(int dt=0;dt<4;++dt)
      #pragma unroll
      for(int r=0;r<4;++r) acc[dt][r] *= aq;
    // ---- read P^T B-fragments (own rows only; lgkmcnt ordering, no barrier) ----
    half8 pf0 = *(const half8*)&myP[l15*PITCH_ + quad*8];
    half8 pf1 = *(const half8*)&myP[l15*PITCH_ + quad*8 + 32];
    // ---- O^T += V^T . P^T ----
    #pragma unroll
    for(int dt=0;dt<4;++dt){
      acc[dt] = __builtin_amdgcn_mfma_f32_16x16x32_f16(vf0[dt], pf0, acc[dt], 0, 0, 0);
      acc[dt] = __builtin_amdgcn_mfma_f32_16x16x32_f16(vf1[dt], pf1, acc[dt], 0, 0, 0);
    }
  }
  // ---- epilogue (wave-private, no barrier) ----
  float lv0 = __shfl(l_run[0], shsrc, 64);
  float lv1 = __shfl(l_run[1], shsrc, 64);
  float lv2 = __shfl(l_run[2], shsrc, 64);
  float lv3 = __shfl(l_run[3], shsrc, 64);
  float lq = (l15 & 2) ? ((l15 & 1) ? lv3 : lv2) : ((l15 & 1) ? lv1 : lv0);
  float inv = 1.0f / lq;
  // transpose O^T -> O rows in private LDS: [q=l15][d=16dt+quad*4+r]
  #pragma unroll
  for(int dt=0;dt<4;++dt)
    #pragma unroll
    for(int r=0;r<4;++r)
      myP[l15*PITCH_ + 16*dt + quad*4 + r] = (f16)(acc[dt][r]*inv);
  int b = bh / H_, h = bh % H_;
  f16* op = AO + ((size_t)(b*N_ + q0 + 16*w + l15))*D_ + h*DH_ + quad*16;
  half8 o0 = *(const half8*)&myP[l15*PITCH_ + quad*16];
  half8 o1 = *(const half8*)&myP[l15*PITCH_ + quad*16 + 8];
  *(half8*)(op)     = o0;
  *(half8*)(op + 8) = o1;
}

// ---------------- 5) Output GEMM (MFMA) ----------------
__global__ __launch_bounds__(256) void out_gemm(const f16* __restrict__ A,
    const f16* __restrict__ W, float* __restrict__ C){
  __shared__ f16 sA[128*32];
  __shared__ f16 sB[128*32];
  int tid = threadIdx.x;
  int w = tid >> 6, lane = tid & 63, quad = lane >> 4, l15 = lane & 15;
  int row0 = blockIdx.y * 128;
  int e0   = blockIdx.x * 128;
  int wr = (w >> 1) * 64, wc = (w & 1) * 64;
  int r0c = tid >> 2,        ci0 = (tid & 3) * 8;
  int r1c = (256+tid) >> 2,  ci1 = (tid & 3) * 8;
  floatx4 acc[4][4];
  #pragma unroll
  for(int i=0;i<4;++i)
    #pragma unroll
    for(int j=0;j<4;++j) acc[i][j] = (floatx4){0.f,0.f,0.f,0.f};

  for(int k0=0; k0<D_; k0+=32){
    __syncthreads();
    gload_lds16(A + (size_t)(row0+r0c)*D_ + k0 + ci0, sA + (size_t)(w*64)*8);
    gload_lds16(A + (size_t)(row0+r1c)*D_ + k0 + ci1, sA + (size_t)(256 + w*64)*8);
    gload_lds16(W + (size_t)(e0 +r0c)*D_ + k0 + ci0, sB + (size_t)(w*64)*8);
    gload_lds16(W + (size_t)(e0 +r1c)*D_ + k0 + ci1, sB + (size_t)(256 + w*64)*8);
    __syncthreads();
    half8 af[4], bf[4];
    #pragma unroll
    for(int mi=0;mi<4;++mi) af[mi] = *(const half8*)&sA[(wr + mi*16 + l15)*32 + quad*8];
    #pragma unroll
    for(int ni=0;ni<4;++ni) bf[ni] = *(const half8*)&sB[(wc + ni*16 + l15)*32 + quad*8];
    #pragma unroll
    for(int mi=0;mi<4;++mi)
      #pragma unroll
      for(int ni=0;ni<4;++ni)
        acc[mi][ni] = __builtin_amdgcn_mfma_f32_16x16x32_f16(af[mi], bf[ni], acc[mi][ni], 0, 0, 0);
  }
  #pragma unroll
  for(int ni=0;ni<4;++ni){
    int col = e0 + wc + ni*16 + l15;
    #pragma unroll
    for(int mi=0;mi<4;++mi){
      int rbase = row0 + wr + mi*16 + quad*4;
      #pragma unroll
      for(int reg=0;reg<4;++reg)
        C[(size_t)(rbase+reg)*D_ + col] = acc[mi][ni][reg];
    }
  }
}

extern "C" void kernel_launch(void* const* d_in, const int* in_sizes, int n_in,
                              void* d_out, int out_size, void* d_ws, size_t ws_size,
                              hipStream_t stream) {
  (void)in_sizes; (void)n_in; (void)out_size; (void)ws_size;
  const float* x      = (const float*)d_in[0];
  const float* coords = (const float*)d_in[1];
  const float* g      = (const float*)d_in[2];
  const float* be     = (const float*)d_in[3];
  const float* wqkv   = (const float*)d_in[4];
  const float* wout   = (const float*)d_in[5];
  float* out = (float*)d_out;
  char* ws = (char*)d_ws;
  const size_t SEG = (size_t)ROWS_ * D_ * 2;   // 12,582,912 B
  f16* xn  = (f16*)(ws + 0*SEG);
  f16* Q   = (f16*)(ws + 1*SEG);
  f16* K   = (f16*)(ws + 2*SEG);
  f16* VT  = (f16*)(ws + 3*SEG);
  f16* AO  = (f16*)(ws + 4*SEG);
  f16* W16 = (f16*)(ws + 5*SEG);                         // 2304*768 fp16
  f16* Wo16= (f16*)(ws + 5*SEG + (size_t)E3_*D_*2);      // 768*768 fp16

  cvt_kernel <<<(E3_*D_/8 + 255)/256, 256, 0, stream>>>(wqkv, W16, E3_*D_/8);
  cvt_kernel <<<(D_*D_/8 + 255)/256, 256, 0, stream>>>(wout, Wo16, D_*D_/8);
  ln_kernel  <<<ROWS_, 256, 0, stream>>>(x, g, be, xn);
  qkv_gemm   <<<dim3(E3_/128, ROWS_/128), 256, 0, stream>>>(xn, W16, Q, K, VT);
  rope_kernel<<<(2*B_*H_*N_)/256, 256, 0, stream>>>(Q, K, coords);
  attn_kernel<<<dim3(N_/64, B_*H_), 256, 0, stream>>>(Q, K, VT, AO);
  out_gemm   <<<dim3(D_/128, ROWS_/128), 256, 0, stream>>>(AO, Wo16, out);
}

// Round 6
// 442.984 us; speedup vs baseline: 1.3356x; 1.3356x over previous
//
#include <hip/hip_runtime.h>

#define B_ 4
#define N_ 2048
#define D_ 768
#define H_ 12
#define DH_ 64
#define ROWS_ (B_*N_)      // 8192
#define E3_ (3*D_)         // 2304

typedef _Float16 f16;
typedef __attribute__((ext_vector_type(8))) _Float16 half8;
typedef __attribute__((ext_vector_type(4))) _Float16 half4;
typedef __attribute__((ext_vector_type(4))) float floatx4;

__device__ __forceinline__ void gload_lds16(const void* g, void* lds){
  __builtin_amdgcn_global_load_lds(
      (const __attribute__((address_space(1))) unsigned int*)g,
      (__attribute__((address_space(3))) unsigned int*)lds, 16, 0, 0);
}

// ---------------- 0) fp32 -> fp16 weight convert ----------------
__global__ __launch_bounds__(256) void cvt_kernel(const float* __restrict__ src,
    f16* __restrict__ dst, int n8){
  int i = blockIdx.x*256 + threadIdx.x;
  if (i < n8){
    float4 a = ((const float4*)src)[2*i];
    float4 b = ((const float4*)src)[2*i+1];
    half8 h;
    h[0]=(f16)a.x; h[1]=(f16)a.y; h[2]=(f16)a.z; h[3]=(f16)a.w;
    h[4]=(f16)b.x; h[5]=(f16)b.y; h[6]=(f16)b.z; h[7]=(f16)b.w;
    *(half8*)(dst + (size_t)i*8) = h;
  }
}

// ---------------- 1) LayerNorm: x (fp32) -> xn (fp16) ----------------
__global__ __launch_bounds__(256) void ln_kernel(const float* __restrict__ x,
    const float* __restrict__ g, const float* __restrict__ be, f16* __restrict__ xn){
  int row = blockIdx.x;
  const float* xr = x + (size_t)row * D_;
  int t = threadIdx.x;
  float v0 = xr[t], v1 = xr[t+256], v2 = xr[t+512];
  float s = v0+v1+v2, ss = v0*v0+v1*v1+v2*v2;
  #pragma unroll
  for(int off=32; off; off>>=1){
    s  += __shfl_down(s,  off, 64);
    ss += __shfl_down(ss, off, 64);
  }
  __shared__ float red[2][4];
  int lane = t & 63, wv = t >> 6;
  if(lane==0){ red[0][wv]=s; red[1][wv]=ss; }
  __syncthreads();
  s  = red[0][0]+red[0][1]+red[0][2]+red[0][3];
  ss = red[1][0]+red[1][1]+red[1][2]+red[1][3];
  float mean = s * (1.0f/D_);
  float var  = ss * (1.0f/D_) - mean*mean;
  float rstd = rsqrtf(var + 1e-5f);
  f16* xo = xn + (size_t)row * D_;
  xo[t]     = (f16)((v0-mean)*rstd*g[t]     + be[t]);
  xo[t+256] = (f16)((v1-mean)*rstd*g[t+256] + be[t+256]);
  xo[t+512] = (f16)((v2-mean)*rstd*g[t+512] + be[t+512]);
}

// ---------------- 2) QKV GEMM (MFMA) ----------------
__global__ __launch_bounds__(256) void qkv_gemm(const f16* __restrict__ A,
    const f16* __restrict__ W, f16* __restrict__ Q, f16* __restrict__ Kt, f16* __restrict__ VT){
  __shared__ f16 sA[128*32];
  __shared__ f16 sB[128*32];
  int tid = threadIdx.x;
  int w = tid >> 6, lane = tid & 63, quad = lane >> 4, l15 = lane & 15;
  int row0 = blockIdx.y * 128;
  int e0   = blockIdx.x * 128;
  int wr = (w >> 1) * 64, wc = (w & 1) * 64;
  int r0c = tid >> 2,        ci0 = (tid & 3) * 8;
  int r1c = (256+tid) >> 2,  ci1 = (tid & 3) * 8;
  floatx4 acc[4][4];
  #pragma unroll
  for(int i=0;i<4;++i)
    #pragma unroll
    for(int j=0;j<4;++j) acc[i][j] = (floatx4){0.f,0.f,0.f,0.f};

  for(int k0=0; k0<D_; k0+=32){
    __syncthreads();
    gload_lds16(A + (size_t)(row0+r0c)*D_ + k0 + ci0, sA + (size_t)(w*64)*8);
    gload_lds16(A + (size_t)(row0+r1c)*D_ + k0 + ci1, sA + (size_t)(256 + w*64)*8);
    gload_lds16(W + (size_t)(e0 +r0c)*D_ + k0 + ci0, sB + (size_t)(w*64)*8);
    gload_lds16(W + (size_t)(e0 +r1c)*D_ + k0 + ci1, sB + (size_t)(256 + w*64)*8);
    __syncthreads();
    half8 af[4], bf[4];
    #pragma unroll
    for(int mi=0;mi<4;++mi) af[mi] = *(const half8*)&sA[(wr + mi*16 + l15)*32 + quad*8];
    #pragma unroll
    for(int ni=0;ni<4;++ni) bf[ni] = *(const half8*)&sB[(wc + ni*16 + l15)*32 + quad*8];
    #pragma unroll
    for(int mi=0;mi<4;++mi)
      #pragma unroll
      for(int ni=0;ni<4;++ni)
        acc[mi][ni] = __builtin_amdgcn_mfma_f32_16x16x32_f16(af[mi], bf[ni], acc[mi][ni], 0, 0, 0);
  }
  int part = e0 / D_;
  int erel = e0 % D_;
  #pragma unroll
  for(int ni=0;ni<4;++ni){
    int col = erel + wc + ni*16 + l15;
    int h = col >> 6, d = col & 63;
    #pragma unroll
    for(int mi=0;mi<4;++mi){
      int rbase = row0 + wr + mi*16 + quad*4;
      int b = rbase >> 11, n = rbase & 2047;   // 4 regs stay in same b, consecutive n
      if (part == 2){
        half4 h4;
        #pragma unroll
        for(int reg=0;reg<4;++reg) h4[reg] = (f16)acc[mi][ni][reg];
        *(half4*)&VT[(((size_t)b*H_ + h)*DH_ + d)*N_ + n] = h4;
      } else {
        f16* dst = (part==0) ? Q : Kt;
        #pragma unroll
        for(int reg=0;reg<4;++reg)
          dst[(((size_t)b*H_ + h)*N_ + n + reg)*DH_ + d] = (f16)acc[mi][ni][reg];
      }
    }
  }
}

// ---------------- 3) RoPE ----------------
__global__ __launch_bounds__(256) void rope_kernel(f16* __restrict__ Q, f16* __restrict__ K,
    const float* __restrict__ coords){
  int t = blockIdx.x*256 + threadIdx.x;
  const int total = B_*H_*N_;
  f16* basep; int idx;
  if (t < total){ basep = Q; idx = t; } else { basep = K; idx = t - total; }
  int n  = idx % N_;
  int bh = idx / N_;
  int b  = bh / H_;
  float c0 = coords[((size_t)b*N_+n)*2 + 0];
  float c1 = coords[((size_t)b*N_+n)*2 + 1];
  f16* rowp = basep + (size_t)idx * DH_;
  #pragma unroll
  for(int ax=0; ax<2; ++ax){
    float coord = ax ? c1 : c0;
    int base = ax*32;
    float tv[32];
    #pragma unroll
    for(int i=0;i<32;++i) tv[i] = (float)rowp[base+i];
    #pragma unroll
    for(int m=0;m<16;++m){
      float fr = exp2f((float)m * (-13.0f/16.0f));
      float ph = coord * fr;
      float sn, cs;
      sincosf(ph, &sn, &cs);
      rowp[base+m]    = (f16)(tv[2*m]*cs - tv[2*m+1]*sn);
      rowp[base+16+m] = (f16)(tv[2*m]*sn + tv[2*m+1]*cs);
    }
  }
}

// ---------------- 4) Flash attention, MFMA fp16: shared-P, 1 barrier/iter (P dbuf) ----------------
// exp2-domain softmax (Q pre-scaled by 0.125*log2e), deferred l reduction.
#define PITCH_ 72
__global__ __launch_bounds__(256) void attn_kernel(const f16* __restrict__ Q,
    const f16* __restrict__ K, const f16* __restrict__ VT, f16* __restrict__ AO){
  __shared__ f16 sP[2][64*PITCH_];
  __shared__ float sAl[2][64];
  __shared__ float sL[64];
  int bh = blockIdx.y;
  int q0 = blockIdx.x * 64;
  int tid = threadIdx.x;
  int w = tid >> 6, lane = tid & 63, quad = lane >> 4, l15 = lane & 15;
  const f16* Qb = Q  + (size_t)bh*N_*DH_;
  const f16* Ks = K  + (size_t)bh*N_*DH_;
  const f16* Vb = VT + (size_t)bh*DH_*N_;   // [d][n]

  const f16* qrow = Qb + (size_t)(q0 + 16*w + l15)*DH_ + quad*8;
  half8 qf0 = *(const half8*)(qrow);
  half8 qf1 = *(const half8*)(qrow + 32);
  // pre-scale Q by 0.125*log2(e) so softmax runs in exp2 domain
  {
    half8 cs8;
    #pragma unroll
    for(int j=0;j<8;++j) cs8[j] = (f16)0.18033688f;
    qf0 = qf0 * cs8;
    qf1 = qf1 * cs8;
  }

  // preload K fragments for kv0 = 0
  half8 kf0[4], kf1[4];
  #pragma unroll
  for(int nt=0;nt<4;++nt){
    const f16* krow = Ks + (size_t)(16*nt + l15)*DH_ + quad*8;
    kf0[nt] = *(const half8*)(krow);
    kf1[nt] = *(const half8*)(krow + 32);
  }

  float m_prev[4], l_run[4];
  #pragma unroll
  for(int r=0;r<4;++r){ m_prev[r] = -1e30f; l_run[r] = 0.0f; }
  floatx4 acc[4];
  #pragma unroll
  for(int qt=0;qt<4;++qt) acc[qt] = (floatx4){0.f,0.f,0.f,0.f};

  const f16* vrow = Vb + (size_t)(16*w + l15)*N_;   // this wave's d-strip row in VT

  int ph = 0;
  for(int kv0=0; kv0<N_; kv0+=64, ph^=1){
    // V^T fragments for THIS tile (consumed after barrier -> latency hidden)
    half8 vf0 = *(const half8*)(vrow + kv0 + quad*8);
    half8 vf1 = *(const half8*)(vrow + kv0 + 32 + quad*8);
    // ---- S = Q K^T (already in exp2 domain) ----
    floatx4 s[4];
    #pragma unroll
    for(int nt=0; nt<4; ++nt){
      floatx4 z = {0.f,0.f,0.f,0.f};
      z = __builtin_amdgcn_mfma_f32_16x16x32_f16(qf0, kf0[nt], z, 0, 0, 0);
      z = __builtin_amdgcn_mfma_f32_16x16x32_f16(qf1, kf1[nt], z, 0, 0, 0);
      s[nt] = z;
    }
    // ---- online softmax ----
    float mx[4], alpha[4], rs[4];
    #pragma unroll
    for(int r=0;r<4;++r)
      mx[r] = fmaxf(fmaxf(s[0][r], s[1][r]), fmaxf(s[2][r], s[3][r]));
    #pragma unroll
    for(int off=1; off<16; off<<=1){
      #pragma unroll
      for(int r=0;r<4;++r) mx[r] = fmaxf(mx[r], __shfl_xor(mx[r], off, 64));
    }
    #pragma unroll
    for(int r=0;r<4;++r){
      float mnew = fmaxf(m_prev[r], mx[r]);
      alpha[r] = exp2f(m_prev[r] - mnew);
      m_prev[r] = mnew;
      rs[r] = 0.0f;
    }
    #pragma unroll
    for(int nt=0;nt<4;++nt){
      #pragma unroll
      for(int r=0;r<4;++r){
        float p = exp2f(s[nt][r] - m_prev[r]);
        s[nt][r] = p;
        rs[r] += p;
      }
    }
    #pragma unroll
    for(int r=0;r<4;++r) l_run[r] = l_run[r]*alpha[r] + rs[r];   // per-lane partial (4 cols)
    // ---- write P + alpha to LDS buffer ph ----
    #pragma unroll
    for(int nt=0;nt<4;++nt)
      #pragma unroll
      for(int r=0;r<4;++r)
        sP[ph][(16*w + quad*4 + r)*PITCH_ + l15 + 16*nt] = (f16)s[nt][r];
    #pragma unroll
    for(int r=0;r<4;++r) if (l15 == r) sAl[ph][16*w + quad*4 + r] = alpha[r];
    __syncthreads();                          // sP[ph] + sAl[ph] published
    // ---- prefetch K fragments for NEXT tile (hidden behind PV) ----
    {
      int kvn = kv0 + 64; if (kvn >= N_) kvn = 0;
      #pragma unroll
      for(int nt=0;nt<4;++nt){
        const f16* krow = Ks + (size_t)(kvn + 16*nt + l15)*DH_ + quad*8;
        kf0[nt] = *(const half8*)(krow);
        kf1[nt] = *(const half8*)(krow + 32);
      }
    }
    // ---- rescale O^T acc (col = q = l15 + 16qt) ----
    #pragma unroll
    for(int qt=0;qt<4;++qt){
      float a = sAl[ph][l15 + 16*qt];
      #pragma unroll
      for(int r=0;r<4;++r) acc[qt][r] *= a;
    }
    // ---- O^T += V^T . P^T ----
    #pragma unroll
    for(int qt=0;qt<4;++qt){
      half8 pf0 = *(const half8*)&sP[ph][(l15 + 16*qt)*PITCH_ + quad*8];
      half8 pf1 = *(const half8*)&sP[ph][(l15 + 16*qt)*PITCH_ + quad*8 + 32];
      acc[qt] = __builtin_amdgcn_mfma_f32_16x16x32_f16(vf0, pf0, acc[qt], 0, 0, 0);
      acc[qt] = __builtin_amdgcn_mfma_f32_16x16x32_f16(vf1, pf1, acc[qt], 0, 0, 0);
    }
  }
  // ---- epilogue: finish deferred l reduction (within each quad's 16 lanes) ----
  #pragma unroll
  for(int off=1; off<16; off<<=1){
    #pragma unroll
    for(int r=0;r<4;++r) l_run[r] += __shfl_xor(l_run[r], off, 64);
  }
  #pragma unroll
  for(int r=0;r<4;++r) if (l15 == r) sL[16*w + quad*4 + r] = l_run[r];
  __syncthreads();                            // last sP reads done + sL ready
  f16* sO = sP[0];
  #pragma unroll
  for(int qt=0;qt<4;++qt){
    float inv = 1.0f / sL[l15 + 16*qt];
    #pragma unroll
    for(int r=0;r<4;++r)
      sO[(l15 + 16*qt)*PITCH_ + 16*w + quad*4 + r] = (f16)(acc[qt][r]*inv);
  }
  __syncthreads();
  int rr = tid >> 2, cc = (tid & 3) * 16;
  int b = bh / H_, h = bh % H_;
  f16* op = AO + ((size_t)(b*N_ + q0 + rr))*D_ + h*DH_ + cc;
  half8 o0 = *(const half8*)&sO[rr*PITCH_ + cc];
  half8 o1 = *(const half8*)&sO[rr*PITCH_ + cc + 8];
  *(half8*)(op)     = o0;
  *(half8*)(op + 8) = o1;
}

// ---------------- 5) Output GEMM (MFMA) ----------------
__global__ __launch_bounds__(256) void out_gemm(const f16* __restrict__ A,
    const f16* __restrict__ W, float* __restrict__ C){
  __shared__ f16 sA[128*32];
  __shared__ f16 sB[128*32];
  int tid = threadIdx.x;
  int w = tid >> 6, lane = tid & 63, quad = lane >> 4, l15 = lane & 15;
  int row0 = blockIdx.y * 128;
  int e0   = blockIdx.x * 128;
  int wr = (w >> 1) * 64, wc = (w & 1) * 64;
  int r0c = tid >> 2,        ci0 = (tid & 3) * 8;
  int r1c = (256+tid) >> 2,  ci1 = (tid & 3) * 8;
  floatx4 acc[4][4];
  #pragma unroll
  for(int i=0;i<4;++i)
    #pragma unroll
    for(int j=0;j<4;++j) acc[i][j] = (floatx4){0.f,0.f,0.f,0.f};

  for(int k0=0; k0<D_; k0+=32){
    __syncthreads();
    gload_lds16(A + (size_t)(row0+r0c)*D_ + k0 + ci0, sA + (size_t)(w*64)*8);
    gload_lds16(A + (size_t)(row0+r1c)*D_ + k0 + ci1, sA + (size_t)(256 + w*64)*8);
    gload_lds16(W + (size_t)(e0 +r0c)*D_ + k0 + ci0, sB + (size_t)(w*64)*8);
    gload_lds16(W + (size_t)(e0 +r1c)*D_ + k0 + ci1, sB + (size_t)(256 + w*64)*8);
    __syncthreads();
    half8 af[4], bf[4];
    #pragma unroll
    for(int mi=0;mi<4;++mi) af[mi] = *(const half8*)&sA[(wr + mi*16 + l15)*32 + quad*8];
    #pragma unroll
    for(int ni=0;ni<4;++ni) bf[ni] = *(const half8*)&sB[(wc + ni*16 + l15)*32 + quad*8];
    #pragma unroll
    for(int mi=0;mi<4;++mi)
      #pragma unroll
      for(int ni=0;ni<4;++ni)
        acc[mi][ni] = __builtin_amdgcn_mfma_f32_16x16x32_f16(af[mi], bf[ni], acc[mi][ni], 0, 0, 0);
  }
  #pragma unroll
  for(int ni=0;ni<4;++ni){
    int col = e0 + wc + ni*16 + l15;
    #pragma unroll
    for(int mi=0;mi<4;++mi){
      int rbase = row0 + wr + mi*16 + quad*4;
      #pragma unroll
      for(int reg=0;reg<4;++reg)
        C[(size_t)(rbase+reg)*D_ + col] = acc[mi][ni][reg];
    }
  }
}

extern "C" void kernel_launch(void* const* d_in, const int* in_sizes, int n_in,
                              void* d_out, int out_size, void* d_ws, size_t ws_size,
                              hipStream_t stream) {
  (void)in_sizes; (void)n_in; (void)out_size; (void)ws_size;
  const float* x      = (const float*)d_in[0];
  const float* coords = (const float*)d_in[1];
  const float* g      = (const float*)d_in[2];
  const float* be     = (const float*)d_in[3];
  const float* wqkv   = (const float*)d_in[4];
  const float* wout   = (const float*)d_in[5];
  float* out = (float*)d_out;
  char* ws = (char*)d_ws;
  const size_t SEG = (size_t)ROWS_ * D_ * 2;   // 12,582,912 B
  f16* xn  = (f16*)(ws + 0*SEG);
  f16* Q   = (f16*)(ws + 1*SEG);
  f16* K   = (f16*)(ws + 2*SEG);
  f16* VT  = (f16*)(ws + 3*SEG);
  f16* AO  = (f16*)(ws + 4*SEG);
  f16* W16 = (f16*)(ws + 5*SEG);                         // 2304*768 fp16
  f16* Wo16= (f16*)(ws + 5*SEG + (size_t)E3_*D_*2);      // 768*768 fp16

  cvt_kernel <<<(E3_*D_/8 + 255)/256, 256, 0, stream>>>(wqkv, W16, E3_*D_/8);
  cvt_kernel <<<(D_*D_/8 + 255)/256, 256, 0, stream>>>(wout, Wo16, D_*D_/8);
  ln_kernel  <<<ROWS_, 256, 0, stream>>>(x, g, be, xn);
  qkv_gemm   <<<dim3(E3_/128, ROWS_/128), 256, 0, stream>>>(xn, W16, Q, K, VT);
  rope_kernel<<<(2*B_*H_*N_)/256, 256, 0, stream>>>(Q, K, coords);
  attn_kernel<<<dim3(N_/64, B_*H_), 256, 0, stream>>>(Q, K, VT, AO);
  out_gemm   <<<dim3(D_/128, ROWS_/128), 256, 0, stream>>>(AO, Wo16, out);
}

// Round 8
// 413.011 us; speedup vs baseline: 1.4325x; 1.0726x over previous
//
#include <hip/hip_runtime.h>

#define B_ 4
#define N_ 2048
#define D_ 768
#define H_ 12
#define DH_ 64
#define ROWS_ (B_*N_)      // 8192
#define E3_ (3*D_)         // 2304

typedef _Float16 f16;
typedef __attribute__((ext_vector_type(8))) _Float16 half8;
typedef __attribute__((ext_vector_type(4))) _Float16 half4;
typedef __attribute__((ext_vector_type(4))) float floatx4;

__device__ __forceinline__ void gload_lds16(const void* g, void* lds){
  __builtin_amdgcn_global_load_lds(
      (const __attribute__((address_space(1))) unsigned int*)g,
      (__attribute__((address_space(3))) unsigned int*)lds, 16, 0, 0);
}

// ---------------- 0) fp32 -> fp16 weight convert ----------------
__global__ __launch_bounds__(256) void cvt_kernel(const float* __restrict__ src,
    f16* __restrict__ dst, int n8){
  int i = blockIdx.x*256 + threadIdx.x;
  if (i < n8){
    float4 a = ((const float4*)src)[2*i];
    float4 b = ((const float4*)src)[2*i+1];
    half8 h;
    h[0]=(f16)a.x; h[1]=(f16)a.y; h[2]=(f16)a.z; h[3]=(f16)a.w;
    h[4]=(f16)b.x; h[5]=(f16)b.y; h[6]=(f16)b.z; h[7]=(f16)b.w;
    *(half8*)(dst + (size_t)i*8) = h;
  }
}

// ---------------- 1) LayerNorm: x (fp32) -> xn (fp16) ----------------
__global__ __launch_bounds__(256) void ln_kernel(const float* __restrict__ x,
    const float* __restrict__ g, const float* __restrict__ be, f16* __restrict__ xn){
  int row = blockIdx.x;
  const float* xr = x + (size_t)row * D_;
  int t = threadIdx.x;
  float v0 = xr[t], v1 = xr[t+256], v2 = xr[t+512];
  float s = v0+v1+v2, ss = v0*v0+v1*v1+v2*v2;
  #pragma unroll
  for(int off=32; off; off>>=1){
    s  += __shfl_down(s,  off, 64);
    ss += __shfl_down(ss, off, 64);
  }
  __shared__ float red[2][4];
  int lane = t & 63, wv = t >> 6;
  if(lane==0){ red[0][wv]=s; red[1][wv]=ss; }
  __syncthreads();
  s  = red[0][0]+red[0][1]+red[0][2]+red[0][3];
  ss = red[1][0]+red[1][1]+red[1][2]+red[1][3];
  float mean = s * (1.0f/D_);
  float var  = ss * (1.0f/D_) - mean*mean;
  float rstd = rsqrtf(var + 1e-5f);
  f16* xo = xn + (size_t)row * D_;
  xo[t]     = (f16)((v0-mean)*rstd*g[t]     + be[t]);
  xo[t+256] = (f16)((v1-mean)*rstd*g[t+256] + be[t+256]);
  xo[t+512] = (f16)((v2-mean)*rstd*g[t+512] + be[t+512]);
}

// ---------------- 2) QKV GEMM (MFMA) ----------------
__global__ __launch_bounds__(256) void qkv_gemm(const f16* __restrict__ A,
    const f16* __restrict__ W, f16* __restrict__ Q, f16* __restrict__ Kt, f16* __restrict__ VT){
  __shared__ f16 sA[128*32];
  __shared__ f16 sB[128*32];
  int tid = threadIdx.x;
  int w = tid >> 6, lane = tid & 63, quad = lane >> 4, l15 = lane & 15;
  int row0 = blockIdx.y * 128;
  int e0   = blockIdx.x * 128;
  int wr = (w >> 1) * 64, wc = (w & 1) * 64;
  int r0c = tid >> 2,        ci0 = (tid & 3) * 8;
  int r1c = (256+tid) >> 2,  ci1 = (tid & 3) * 8;
  floatx4 acc[4][4];
  #pragma unroll
  for(int i=0;i<4;++i)
    #pragma unroll
    for(int j=0;j<4;++j) acc[i][j] = (floatx4){0.f,0.f,0.f,0.f};

  for(int k0=0; k0<D_; k0+=32){
    __syncthreads();
    gload_lds16(A + (size_t)(row0+r0c)*D_ + k0 + ci0, sA + (size_t)(w*64)*8);
    gload_lds16(A + (size_t)(row0+r1c)*D_ + k0 + ci1, sA + (size_t)(256 + w*64)*8);
    gload_lds16(W + (size_t)(e0 +r0c)*D_ + k0 + ci0, sB + (size_t)(w*64)*8);
    gload_lds16(W + (size_t)(e0 +r1c)*D_ + k0 + ci1, sB + (size_t)(256 + w*64)*8);
    __syncthreads();
    half8 af[4], bf[4];
    #pragma unroll
    for(int mi=0;mi<4;++mi) af[mi] = *(const half8*)&sA[(wr + mi*16 + l15)*32 + quad*8];
    #pragma unroll
    for(int ni=0;ni<4;++ni) bf[ni] = *(const half8*)&sB[(wc + ni*16 + l15)*32 + quad*8];
    #pragma unroll
    for(int mi=0;mi<4;++mi)
      #pragma unroll
      for(int ni=0;ni<4;++ni)
        acc[mi][ni] = __builtin_amdgcn_mfma_f32_16x16x32_f16(af[mi], bf[ni], acc[mi][ni], 0, 0, 0);
  }
  int part = e0 / D_;
  int erel = e0 % D_;
  #pragma unroll
  for(int ni=0;ni<4;++ni){
    int col = erel + wc + ni*16 + l15;
    int h = col >> 6, d = col & 63;
    #pragma unroll
    for(int mi=0;mi<4;++mi){
      int rbase = row0 + wr + mi*16 + quad*4;
      int b = rbase >> 11, n = rbase & 2047;   // 4 regs stay in same b, consecutive n
      if (part == 2){
        half4 h4;
        #pragma unroll
        for(int reg=0;reg<4;++reg) h4[reg] = (f16)acc[mi][ni][reg];
        *(half4*)&VT[(((size_t)b*H_ + h)*DH_ + d)*N_ + n] = h4;
      } else {
        f16* dst = (part==0) ? Q : Kt;
        #pragma unroll
        for(int reg=0;reg<4;++reg)
          dst[(((size_t)b*H_ + h)*N_ + n + reg)*DH_ + d] = (f16)acc[mi][ni][reg];
      }
    }
  }
}

// ---------------- 3) RoPE ----------------
__global__ __launch_bounds__(256) void rope_kernel(f16* __restrict__ Q, f16* __restrict__ K,
    const float* __restrict__ coords){
  int t = blockIdx.x*256 + threadIdx.x;
  const int total = B_*H_*N_;
  f16* basep; int idx;
  if (t < total){ basep = Q; idx = t; } else { basep = K; idx = t - total; }
  int n  = idx % N_;
  int bh = idx / N_;
  int b  = bh / H_;
  float c0 = coords[((size_t)b*N_+n)*2 + 0];
  float c1 = coords[((size_t)b*N_+n)*2 + 1];
  f16* rowp = basep + (size_t)idx * DH_;
  #pragma unroll
  for(int ax=0; ax<2; ++ax){
    float coord = ax ? c1 : c0;
    int base = ax*32;
    float tv[32];
    #pragma unroll
    for(int i=0;i<32;++i) tv[i] = (float)rowp[base+i];
    #pragma unroll
    for(int m=0;m<16;++m){
      float fr = exp2f((float)m * (-13.0f/16.0f));
      float ph = coord * fr;
      float sn, cs;
      sincosf(ph, &sn, &cs);
      rowp[base+m]    = (f16)(tv[2*m]*cs - tv[2*m+1]*sn);
      rowp[base+16+m] = (f16)(tv[2*m]*sn + tv[2*m+1]*cs);
    }
  }
}

// ---------------- 4) Flash attention: S^T layout, per-lane softmax state ----------------
// Wave w owns q rows [q0+16w, q0+16w+16). S^T = K·Q^T: lane owns q-col l15,
// kv = 16nt+quad*4+r. m/alpha/l are lane scalars. P wave-private in LDS.
// V^T tile staged via double-buffered LDS (1 barrier/iter).
#define PP_ 72
#define VP_ 72
__global__ __launch_bounds__(256) void attn_kernel(const f16* __restrict__ Q,
    const f16* __restrict__ K, const f16* __restrict__ VT, f16* __restrict__ AO){
  __shared__ f16 sV[2][64*VP_];
  __shared__ f16 sP[4][16*PP_];
  int bh = blockIdx.y;
  int q0 = blockIdx.x * 64;
  int tid = threadIdx.x;
  int w = tid >> 6, lane = tid & 63, quad = lane >> 4, l15 = lane & 15;
  const f16* Qb = Q  + (size_t)bh*N_*DH_;
  const f16* Ks = K  + (size_t)bh*N_*DH_;
  const f16* Vb = VT + (size_t)bh*DH_*N_;   // [d][n]
  f16* myP = &sP[w][0];

  // V staging mapping: thread covers row d=tid>>2, 32B chunk (tid&3)
  int sd = tid >> 2, sc = tid & 3;
  const f16* vsrc = Vb + (size_t)sd*N_ + sc*16;
  int svoff = sd*VP_ + sc*16;

  // Q fragment (B-operand): n=q=l15 (strip-local), k=d=quad*8+j; pre-scaled
  const f16* qrow = Qb + (size_t)(q0 + 16*w + l15)*DH_ + quad*8;
  half8 qf0 = *(const half8*)(qrow);
  half8 qf1 = *(const half8*)(qrow + 32);
  {
    half8 cs8;
    #pragma unroll
    for(int j=0;j<8;++j) cs8[j] = (f16)0.18033688f;   // 0.125 * log2(e)
    qf0 = qf0 * cs8;
    qf1 = qf1 * cs8;
  }

  // K fragments (A-operand) for kv0=0: m=kv=16nt+l15, k=d=quad*8+j
  half8 kf0[4], kf1[4];
  #pragma unroll
  for(int nt=0;nt<4;++nt){
    const f16* krow = Ks + (size_t)(16*nt + l15)*DH_ + quad*8;
    kf0[nt] = *(const half8*)(krow);
    kf1[nt] = *(const half8*)(krow + 32);
  }

  // preload V tile 0
  {
    half8 g0 = *(const half8*)(vsrc);
    half8 g1 = *(const half8*)(vsrc + 8);
    *(half8*)&sV[0][svoff]     = g0;
    *(half8*)&sV[0][svoff + 8] = g1;
  }

  float m_prev = -1e30f, l_run = 0.0f;
  floatx4 acc[4];                       // O^T: acc[dt][r] = O^T[16dt+quad*4+r][q=l15]
  #pragma unroll
  for(int dt=0;dt<4;++dt) acc[dt] = (floatx4){0.f,0.f,0.f,0.f};
  __syncthreads();

  int ph = 0;
  for(int kv0=0; kv0<N_; kv0+=64, ph^=1){
    int kvn = kv0 + 64; if (kvn >= N_) kvn = 0;
    // issue next V-tile global loads (consumed at loop bottom)
    half8 g0 = *(const half8*)(vsrc + kvn);
    half8 g1 = *(const half8*)(vsrc + kvn + 8);
    // ---- S^T = K Q^T ----
    floatx4 s[4];
    #pragma unroll
    for(int nt=0; nt<4; ++nt){
      floatx4 z = {0.f,0.f,0.f,0.f};
      z = __builtin_amdgcn_mfma_f32_16x16x32_f16(kf0[nt], qf0, z, 0, 0, 0);
      z = __builtin_amdgcn_mfma_f32_16x16x32_f16(kf1[nt], qf1, z, 0, 0, 0);
      s[nt] = z;
    }
    // ---- softmax: lane owns q-col l15; 16 vals local + 2 cross-quad reduces ----
    float mx = s[0][0];
    #pragma unroll
    for(int nt=0;nt<4;++nt)
      #pragma unroll
      for(int r=0;r<4;++r) if(nt|r) mx = fmaxf(mx, s[nt][r]);
    mx = fmaxf(mx, __shfl_xor(mx, 16, 64));
    mx = fmaxf(mx, __shfl_xor(mx, 32, 64));
    float mnew = fmaxf(m_prev, mx);
    float alpha = exp2f(m_prev - mnew);
    m_prev = mnew;
    float rs = 0.0f;
    #pragma unroll
    for(int nt=0;nt<4;++nt)
      #pragma unroll
      for(int r=0;r<4;++r){
        float p = exp2f(s[nt][r] - mnew);
        s[nt][r] = p;
        rs += p;
      }
    l_run = l_run*alpha + rs;            // quad-partial; reduced in epilogue
    // ---- P write: 4x ds_write_b64, wave-private ----
    #pragma unroll
    for(int nt=0;nt<4;++nt){
      half4 h;
      h[0]=(f16)s[nt][0]; h[1]=(f16)s[nt][1];
      h[2]=(f16)s[nt][2]; h[3]=(f16)s[nt][3];
      *(half4*)&myP[l15*PP_ + 16*nt + quad*4] = h;
    }
    // ---- prefetch K fragments for next tile ----
    #pragma unroll
    for(int nt=0;nt<4;++nt){
      const f16* krow = Ks + (size_t)(kvn + 16*nt + l15)*DH_ + quad*8;
      kf0[nt] = *(const half8*)(krow);
      kf1[nt] = *(const half8*)(krow + 32);
    }
    // ---- P^T B-frags (own row, contiguous) ----
    half8 pf0 = *(const half8*)&myP[l15*PP_ + quad*8];
    half8 pf1 = *(const half8*)&myP[l15*PP_ + quad*8 + 32];
    // ---- rescale O^T (alpha already in-lane) ----
    #pragma unroll
    for(int dt=0;dt<4;++dt)
      #pragma unroll
      for(int r=0;r<4;++r) acc[dt][r] *= alpha;
    // ---- O^T += V^T · P^T (V frags from staged LDS) ----
    {
      const f16* sv = &sV[ph][0];
      #pragma unroll
      for(int dt=0;dt<4;++dt){
        half8 v0 = *(const half8*)&sv[(16*dt + l15)*VP_ + quad*8];
        half8 v1 = *(const half8*)&sv[(16*dt + l15)*VP_ + quad*8 + 32];
        acc[dt] = __builtin_amdgcn_mfma_f32_16x16x32_f16(v0, pf0, acc[dt], 0, 0, 0);
        acc[dt] = __builtin_amdgcn_mfma_f32_16x16x32_f16(v1, pf1, acc[dt], 0, 0, 0);
      }
    }
    // ---- publish next V tile ----
    {
      f16* dstv = &sV[ph^1][0];
      *(half8*)&dstv[svoff]     = g0;
      *(half8*)&dstv[svoff + 8] = g1;
    }
    __syncthreads();
  }
  // ---- epilogue ----
  l_run += __shfl_xor(l_run, 16, 64);
  l_run += __shfl_xor(l_run, 32, 64);
  float inv = 1.0f / l_run;
  #pragma unroll
  for(int dt=0;dt<4;++dt){
    half4 h;
    h[0]=(f16)(acc[dt][0]*inv); h[1]=(f16)(acc[dt][1]*inv);
    h[2]=(f16)(acc[dt][2]*inv); h[3]=(f16)(acc[dt][3]*inv);
    *(half4*)&myP[l15*PP_ + 16*dt + quad*4] = h;   // O[q=l15][d]
  }
  int b = bh / H_, h = bh % H_;
  f16* op = AO + ((size_t)(b*N_ + q0 + 16*w + l15))*D_ + h*DH_ + quad*16;
  half8 o0 = *(const half8*)&myP[l15*PP_ + quad*16];
  half8 o1 = *(const half8*)&myP[l15*PP_ + quad*16 + 8];
  *(half8*)(op)     = o0;
  *(half8*)(op + 8) = o1;
}

// ---------------- 5) Output GEMM (MFMA) ----------------
__global__ __launch_bounds__(256) void out_gemm(const f16* __restrict__ A,
    const f16* __restrict__ W, float* __restrict__ C){
  __shared__ f16 sA[128*32];
  __shared__ f16 sB[128*32];
  int tid = threadIdx.x;
  int w = tid >> 6, lane = tid & 63, quad = lane >> 4, l15 = lane & 15;
  int row0 = blockIdx.y * 128;
  int e0   = blockIdx.x * 128;
  int wr = (w >> 1) * 64, wc = (w & 1) * 64;
  int r0c = tid >> 2,        ci0 = (tid & 3) * 8;
  int r1c = (256+tid) >> 2,  ci1 = (tid & 3) * 8;
  floatx4 acc[4][4];
  #pragma unroll
  for(int i=0;i<4;++i)
    #pragma unroll
    for(int j=0;j<4;++j) acc[i][j] = (floatx4){0.f,0.f,0.f,0.f};

  for(int k0=0; k0<D_; k0+=32){
    __syncthreads();
    gload_lds16(A + (size_t)(row0+r0c)*D_ + k0 + ci0, sA + (size_t)(w*64)*8);
    gload_lds16(A + (size_t)(row0+r1c)*D_ + k0 + ci1, sA + (size_t)(256 + w*64)*8);
    gload_lds16(W + (size_t)(e0 +r0c)*D_ + k0 + ci0, sB + (size_t)(w*64)*8);
    gload_lds16(W + (size_t)(e0 +r1c)*D_ + k0 + ci1, sB + (size_t)(256 + w*64)*8);
    __syncthreads();
    half8 af[4], bf[4];
    #pragma unroll
    for(int mi=0;mi<4;++mi) af[mi] = *(const half8*)&sA[(wr + mi*16 + l15)*32 + quad*8];
    #pragma unroll
    for(int ni=0;ni<4;++ni) bf[ni] = *(const half8*)&sB[(wc + ni*16 + l15)*32 + quad*8];
    #pragma unroll
    for(int mi=0;mi<4;++mi)
      #pragma unroll
      for(int ni=0;ni<4;++ni)
        acc[mi][ni] = __builtin_amdgcn_mfma_f32_16x16x32_f16(af[mi], bf[ni], acc[mi][ni], 0, 0, 0);
  }
  #pragma unroll
  for(int ni=0;ni<4;++ni){
    int col = e0 + wc + ni*16 + l15;
    #pragma unroll
    for(int mi=0;mi<4;++mi){
      int rbase = row0 + wr + mi*16 + quad*4;
      #pragma unroll
      for(int reg=0;reg<4;++reg)
        C[(size_t)(rbase+reg)*D_ + col] = acc[mi][ni][reg];
    }
  }
}

extern "C" void kernel_launch(void* const* d_in, const int* in_sizes, int n_in,
                              void* d_out, int out_size, void* d_ws, size_t ws_size,
                              hipStream_t stream) {
  (void)in_sizes; (void)n_in; (void)out_size; (void)ws_size;
  const float* x      = (const float*)d_in[0];
  const float* coords = (const float*)d_in[1];
  const float* g      = (const float*)d_in[2];
  const float* be     = (const float*)d_in[3];
  const float* wqkv   = (const float*)d_in[4];
  const float* wout   = (const float*)d_in[5];
  float* out = (float*)d_out;
  char* ws = (char*)d_ws;
  const size_t SEG = (size_t)ROWS_ * D_ * 2;   // 12,582,912 B
  f16* xn  = (f16*)(ws + 0*SEG);
  f16* Q   = (f16*)(ws + 1*SEG);
  f16* K   = (f16*)(ws + 2*SEG);
  f16* VT  = (f16*)(ws + 3*SEG);
  f16* AO  = (f16*)(ws + 4*SEG);
  f16* W16 = (f16*)(ws + 5*SEG);                         // 2304*768 fp16
  f16* Wo16= (f16*)(ws + 5*SEG + (size_t)E3_*D_*2);      // 768*768 fp16

  cvt_kernel <<<(E3_*D_/8 + 255)/256, 256, 0, stream>>>(wqkv, W16, E3_*D_/8);
  cvt_kernel <<<(D_*D_/8 + 255)/256, 256, 0, stream>>>(wout, Wo16, D_*D_/8);
  ln_kernel  <<<ROWS_, 256, 0, stream>>>(x, g, be, xn);
  qkv_gemm   <<<dim3(E3_/128, ROWS_/128), 256, 0, stream>>>(xn, W16, Q, K, VT);
  rope_kernel<<<(2*B_*H_*N_)/256, 256, 0, stream>>>(Q, K, coords);
  attn_kernel<<<dim3(N_/64, B_*H_), 256, 0, stream>>>(Q, K, VT, AO);
  out_gemm   <<<dim3(D_/128, ROWS_/128), 256, 0, stream>>>(AO, Wo16, out);
}